// Round 4
// baseline (130.282 us; speedup 1.0000x reference)
//
#include <hip/hip_runtime.h>
#include <math.h>

// Problem constants: B=512, Q=100, C=81, V=117
#define Bn 512
#define Qn 100
#define Cn 81
#define Vn 117
#define NQ (Bn * Qn)            // 51200

// d_out layout (floats), outputs concatenated flat in return order:
// hoi_scores (B,Q,V) | obj_labels (B,Q) | sub_boxes (B,Q,4) | obj_boxes (B,Q,4) | keep (B,Q)
#define OFF_HOI  0
#define OFF_LAB  (NQ * Vn)
#define OFF_SUB  (OFF_LAB + NQ)
#define OFF_OBJ  (OFF_SUB + NQ * 4)
#define OFF_KEEP (OFF_OBJ + NQ * 4)

__device__ __forceinline__ float frcp(float x) { return __builtin_amdgcn_rcpf(x); }

// ---- Kernel A: scoring. 1 query per 16-lane group, 16 queries/block.
// No LDS, no barriers, no loops: latency hidden by occupancy (~32 waves/CU
// at VGPR~32), not ILP. CM read from global (38 KB, L1/L2-resident).
__global__ __launch_bounds__(256) void hoi_score(
    const float* __restrict__ obj_logits,
    const float* __restrict__ verb_logits,
    const float* __restrict__ sub_boxes,
    const float* __restrict__ obj_boxes,
    const float* __restrict__ cm,           // correct_mat, natural (V x C) layout
    const int*   __restrict__ target_sizes,
    float* __restrict__ out)
{
    const int tid = threadIdx.x;
    const int t   = tid & 15;               // lane within group
    const int g   = tid >> 4;               // group 0..15
    const int idx = blockIdx.x * 16 + g;    // grid = NQ/16 = 3200, no bounds needed
    const int b   = idx / Qn;

    // boxes: lanes t<2 handle sub(t=0)/obj(t=1); proven round-0 pattern
    if (t < 2) {
        const float ih = (float)target_sizes[2 * b + 0];
        const float iw = (float)target_sizes[2 * b + 1];
        const float4 bx = ((const float4*)(t == 0 ? sub_boxes : obj_boxes))[idx];
        float4 r;
        r.x = (bx.x - 0.5f * bx.z) * iw;
        r.y = (bx.y - 0.5f * bx.w) * ih;
        r.z = (bx.x + 0.5f * bx.z) * iw;
        r.w = (bx.y + 0.5f * bx.w) * ih;
        ((float4*)(out + (t == 0 ? OFF_SUB : OFF_OBJ)))[idx] = r;
    }

    const float* lg = obj_logits + (size_t)idx * Cn;
    const float* vl = verb_logits + (size_t)idx * Vn;

    float l0 = lg[t], l1 = lg[t + 16], l2 = lg[t + 32],
          l3 = lg[t + 48], l4 = lg[t + 64], l5 = lg[80];
    float w0 = vl[t], w1 = vl[t + 16], w2 = vl[t + 32], w3 = vl[t + 48],
          w4 = vl[t + 64], w5 = vl[t + 80], w6 = vl[t + 96];
    float w7 = (t < 5) ? vl[112 + t] : 0.f;

    // argmax over cols [0,80): keep lowest col on tie
    float v = l0; int vid = t;
    if (l1 > v) { v = l1; vid = t + 16; }
    if (l2 > v) { v = l2; vid = t + 32; }
    if (l3 > v) { v = l3; vid = t + 48; }
    if (l4 > v) { v = l4; vid = t + 64; }
    #pragma unroll
    for (int o = 8; o; o >>= 1) {
        float ov = __shfl_xor(v, o, 64);
        int   oi = __shfl_xor(vid, o, 64);
        if (ov > v || (ov == v && oi < vid)) { v = ov; vid = oi; }
    }

    // sum(exp) over all 81 (logits ~N(0,1), exp safe)
    float e = __expf(l0) + __expf(l1) + __expf(l2) + __expf(l3) + __expf(l4);
    #pragma unroll
    for (int o = 8; o; o >>= 1) e += __shfl_xor(e, o, 64);
    e += __expf(l5);

    const int   label     = vid;            // group-uniform after reduction
    const float obj_score = __expf(v) * frcp(e);

    // verb sigmoid * obj_score * mask; store hoi direct from regs.
    // CM gather: cm[(col)*Cn + label], L1/L2-hot.
    float* hout = out + OFF_HOI + (size_t)idx * Vn;
    const float* cmrow = cm + label;
    float mx = 0.f, h;
    h = frcp(1.f + __expf(-w0)) * obj_score * cmrow[(t      ) * Cn]; hout[t      ] = h; mx = fmaxf(mx, h);
    h = frcp(1.f + __expf(-w1)) * obj_score * cmrow[(t +  16) * Cn]; hout[t +  16] = h; mx = fmaxf(mx, h);
    h = frcp(1.f + __expf(-w2)) * obj_score * cmrow[(t +  32) * Cn]; hout[t +  32] = h; mx = fmaxf(mx, h);
    h = frcp(1.f + __expf(-w3)) * obj_score * cmrow[(t +  48) * Cn]; hout[t +  48] = h; mx = fmaxf(mx, h);
    h = frcp(1.f + __expf(-w4)) * obj_score * cmrow[(t +  64) * Cn]; hout[t +  64] = h; mx = fmaxf(mx, h);
    h = frcp(1.f + __expf(-w5)) * obj_score * cmrow[(t +  80) * Cn]; hout[t +  80] = h; mx = fmaxf(mx, h);
    h = frcp(1.f + __expf(-w6)) * obj_score * cmrow[(t +  96) * Cn]; hout[t +  96] = h; mx = fmaxf(mx, h);
    if (t < 5) {
        h = frcp(1.f + __expf(-w7)) * obj_score * cmrow[(112 + t) * Cn];
        hout[112 + t] = h; mx = fmaxf(mx, h);
    }
    #pragma unroll
    for (int o = 8; o; o >>= 1) mx = fmaxf(mx, __shfl_xor(mx, o, 64));

    if (t == 0) {
        out[OFF_LAB + idx]  = (float)label;
        out[OFF_KEEP + idx] = mx;           // temp stash of max_scores
    }
}

// ---- Kernel B: per-image NMS. 256 thr: LDS rank-sort -> suppression matrix
// (2 units x 128 cols x ~50 rows, next-row prefetch) -> prefetched serial
// chain -> keep scatter (overwrites the max_scores stash).
__global__ __launch_bounds__(256) void hoi_nms(float* __restrict__ out)
{
    __shared__ float  sc[Qn];
    __shared__ float4 Ssub[Qn], Sobj[Qn], Smeta[Qn];    // meta={sarea,oarea,lab,orig}
    __shared__ ulonglong2 RR[Qn];                       // suppression rows (0..98)

    const int b   = blockIdx.x;
    const int tid = threadIdx.x;

    // load per-query data; registers persist across the barrier
    float  kv = 0.f, labf = 0.f;
    float4 sb = make_float4(0.f, 0.f, 0.f, 0.f), ob = sb;
    if (tid < Qn) {
        const int idx = b * Qn + tid;
        kv   = out[OFF_KEEP + idx];
        sb   = ((const float4*)(out + OFF_SUB))[idx];
        ob   = ((const float4*)(out + OFF_OBJ))[idx];
        labf = out[OFF_LAB + idx];
        sc[tid] = kv;
    }
    __syncthreads();

    // stable rank sort
    if (tid < Qn) {
        int r = 0;
        #pragma unroll 4
        for (int j = 0; j < Qn; j++) {
            float sj = sc[j];
            r += (sj > kv) || (sj == kv && j < tid);
        }
        Ssub[r] = sb;
        Sobj[r] = ob;
        Smeta[r] = make_float4((sb.z - sb.x + 1.f) * (sb.w - sb.y + 1.f),
                               (ob.z - ob.x + 1.f) * (ob.w - ob.y + 1.f),
                               labf, (float)tid);
    }
    __syncthreads();

    // suppression rows: 2 units x 128 cols; unit 0 rows 0..49, unit 1 rows 50..98
    {
        const int tc   = tid & 127;         // sorted column j
        const int uq   = tid >> 7;          // unit 0..1
        const int lane = tid & 63;
        const int sub  = (tid >> 6) & 1;    // which 64-bit word of the row
        const bool jv  = (tc < Qn);

        float4 js = make_float4(0.f, 0.f, 0.f, 0.f), jo = js, jm = js;
        if (jv) { js = Ssub[tc]; jo = Sobj[tc]; jm = Smeta[tc]; }

        const int i0 = uq * 50;
        const int i1 = (i0 + 50 < Qn - 1) ? i0 + 50 : Qn - 1;   // 50 / 49 rows
        float4 is = Ssub[i0], io = Sobj[i0], im = Smeta[i0];
        for (int i = i0; i < i1; i++) {
            const int inx = (i + 1 < i1) ? i + 1 : i;
            float4 isn = Ssub[inx], ion = Sobj[inx], imn = Smeta[inx];  // prefetch
            float ww = fmaxf(0.f, fminf(is.z, js.z) - fmaxf(is.x, js.x) + 1.f);
            float hh = fmaxf(0.f, fminf(is.w, js.w) - fmaxf(is.y, js.y) + 1.f);
            float inter = ww * hh;
            float iou_s = inter / (im.x + jm.x - inter);
            ww = fmaxf(0.f, fminf(io.z, jo.z) - fmaxf(io.x, jo.x) + 1.f);
            hh = fmaxf(0.f, fminf(io.w, jo.w) - fmaxf(io.y, jo.y) + 1.f);
            inter = ww * hh;
            float iou_o = inter / (im.y + jm.y - inter);
            bool cond = jv && (tc > i) && (jm.z == im.z) && (iou_s * sqrtf(iou_o) > 0.7f);
            unsigned long long m = __ballot(cond);
            if (lane == 0) ((unsigned long long*)&RR[i])[sub] = m;
            is = isn; io = ion; im = imn;
        }
    }
    __syncthreads();

    // serial greedy chain (wave 0, prefetched) + keep scatter
    if (tid < 64) {
        unsigned long long s0 = 0ull, s1 = 0ull;
        ulonglong2 r = RR[0];
        for (int k = 0; k < Qn - 1; k++) {
            ulonglong2 rn = RR[(k + 1 < Qn - 1) ? k + 1 : k];   // prefetch next
            unsigned long long dead = ((k < 64 ? s0 : s1) >> (k & 63)) & 1ull;
            if (!dead) { s0 |= r.x; s1 |= r.y; }
            r = rn;
        }
        float* keepp = out + OFF_KEEP + (size_t)b * Qn;
        keepp[(int)Smeta[tid].w] = ((s0 >> tid) & 1ull) ? 0.f : 1.f;
        if (tid < 36)
            keepp[(int)Smeta[64 + tid].w] = ((s1 >> tid) & 1ull) ? 0.f : 1.f;
    }
}

extern "C" void kernel_launch(void* const* d_in, const int* in_sizes, int n_in,
                              void* d_out, int out_size, void* d_ws, size_t ws_size,
                              hipStream_t stream) {
    const float* obj_logits   = (const float*)d_in[0];
    const float* verb_logits  = (const float*)d_in[1];
    const float* sub_boxes    = (const float*)d_in[2];
    const float* obj_boxes    = (const float*)d_in[3];
    const float* correct_mat  = (const float*)d_in[4];
    const int*   target_sizes = (const int*)d_in[5];
    float* out = (float*)d_out;
    (void)d_ws; (void)ws_size; (void)in_sizes; (void)n_in; (void)out_size;

    hoi_score<<<NQ / 16, 256, 0, stream>>>(obj_logits, verb_logits, sub_boxes,
                                           obj_boxes, correct_mat, target_sizes, out);
    hoi_nms<<<Bn, 256, 0, stream>>>(out);
}